// Round 1
// baseline (889.501 us; speedup 1.0000x reference)
//
#include <hip/hip_runtime.h>
#include <hip/hip_bf16.h>

typedef __attribute__((ext_vector_type(8))) short short8;
typedef __attribute__((ext_vector_type(4))) short short4v;
typedef __attribute__((ext_vector_type(4))) float f32x4;

#define MFMA16(a,b,c) __builtin_amdgcn_mfma_f32_16x16x32_bf16(a,b,c,0,0,0)

static __device__ __forceinline__ short f2bf(float f){
    union{float f;unsigned u;}x; x.f=f;
    unsigned r=(x.u+0x7FFFu+((x.u>>16)&1u))>>16;
    return (short)r;
}

// B=2, S=2048, H=32, HK=8, D=128, G=4
constexpr int S_=2048, H_=32, HK_=8, D_=128;
constexpr int QBLK=64, KVBLK=64;

__global__ __launch_bounds__(256) void attn_fwd(
    const float* __restrict__ q, const float* __restrict__ k,
    const float* __restrict__ v, float* __restrict__ out)
{
    // K tile: [64][128] bf16, swizzled rows of 256B
    __shared__ __align__(16) unsigned char kls[KVBLK*D_*2];      // 16 KB
    // V^T tile: [128][64] bf16, swizzled rows of 128B
    __shared__ __align__(16) unsigned char vls[D_*KVBLK*2];      // 16 KB
    // per-wave P: [4][16][64] bf16, swizzled rows of 128B
    __shared__ __align__(16) unsigned char pls[4*16*KVBLK*2];    // 8 KB

    const int bid  = blockIdx.x;
    const int tile = 31 - (bid & 31);        // heavy (large-tile) blocks first
    const int h    = (bid >> 5) & 31;
    const int b    = bid >> 10;
    const int hk   = h >> 2;                 // G = 4

    const int tid  = threadIdx.x;
    const int wave = tid >> 6;
    const int lane = tid & 63;
    const int lr   = lane & 15;
    const int lg   = lane >> 4;

    // 1/sqrt(128) * log2(e): softmax in base-2
    const float qscale = 0.08838834764831845f * 1.4426950408889634f;

    const int q0 = tile * QBLK;

    // ---- load Q fragments (16 rows per wave), fp32 -> bf16, scale folded ----
    short8 qf[4];
    {
        const int qrow = q0 + wave*16 + lr;
        const float* qp = q + ((size_t)(b*S_ + qrow)*H_ + h)*D_;
        #pragma unroll
        for(int kk=0;kk<4;kk++){
            int d0 = kk*32 + lg*8;
            f32x4 a = *(const f32x4*)(qp + d0);
            f32x4 c = *(const f32x4*)(qp + d0 + 4);
            short8 f;
            f[0]=f2bf(a[0]*qscale); f[1]=f2bf(a[1]*qscale);
            f[2]=f2bf(a[2]*qscale); f[3]=f2bf(a[3]*qscale);
            f[4]=f2bf(c[0]*qscale); f[5]=f2bf(c[1]*qscale);
            f[6]=f2bf(c[2]*qscale); f[7]=f2bf(c[3]*qscale);
            qf[kk]=f;
        }
    }

    f32x4 ot[8];
    #pragma unroll
    for(int i=0;i<8;i++) ot[i]=(f32x4)0.f;
    float m_r[4], l_r[4];
    #pragma unroll
    for(int r=0;r<4;r++){ m_r[r]=-1e30f; l_r[r]=0.f; }

    const int nkv = tile + 1;
    for(int kvt=0; kvt<nkv; ++kvt){
        const int kv0 = kvt*KVBLK;
        __syncthreads();   // previous iteration's K/V reads done before overwrite
        // ---- stage K (swizzled) and V^T (swizzled) as bf16 ----
        {
            const float* kbase = k + ((size_t)(b*S_ + kv0)*HK_ + hk)*D_;
            const float* vbase = v + ((size_t)(b*S_ + kv0)*HK_ + hk)*D_;
            #pragma unroll
            for(int i=0;i<8;i++){
                int e   = (i*256 + tid)*4;
                int row = e >> 7;          // kv row 0..63
                int col = e & 127;         // d, multiple of 4
                f32x4 k4 = *(const f32x4*)(kbase + (size_t)row*HK_*D_ + col);
                short4v ks;
                ks[0]=f2bf(k4[0]); ks[1]=f2bf(k4[1]); ks[2]=f2bf(k4[2]); ks[3]=f2bf(k4[3]);
                int kaddr = (row*256 + col*2) ^ ((row&7)<<4);
                *(short4v*)(kls + kaddr) = ks;
                f32x4 v4 = *(const f32x4*)(vbase + (size_t)row*HK_*D_ + col);
                #pragma unroll
                for(int j=0;j<4;j++){
                    int dd = col + j;
                    int vaddr = (dd*128 + row*2) ^ ((dd&7)<<4);
                    *(short*)(vls + vaddr) = f2bf(v4[j]);
                }
            }
        }
        __syncthreads();

        // ---- S = Q K^T : 4 kv-subtiles x 4 d-chunks of MFMA ----
        f32x4 sac[4];
        #pragma unroll
        for(int t=0;t<4;t++) sac[t]=(f32x4)0.f;
        #pragma unroll
        for(int t=0;t<4;t++){
            int kvr = t*16 + lr;
            #pragma unroll
            for(int kk=0;kk<4;kk++){
                int addr = (kvr*256 + kk*64 + lg*16) ^ ((kvr&7)<<4);
                short8 kf = *(const short8*)(kls + addr);
                sac[t] = MFMA16(qf[kk], kf, sac[t]);
            }
        }
        // ---- causal mask (only diagonal tile) ----
        if (kvt == tile){
            #pragma unroll
            for(int t=0;t<4;t++){
                #pragma unroll
                for(int r=0;r<4;r++){
                    int gq  = q0 + wave*16 + lg*4 + r;
                    int gkv = kv0 + t*16 + lr;
                    if (gkv > gq) sac[t][r] = -1e30f;
                }
            }
        }
        // ---- online softmax (base-2) ----
        float pm[4];
        #pragma unroll
        for(int r=0;r<4;r++){
            float mx = fmaxf(fmaxf(sac[0][r],sac[1][r]),fmaxf(sac[2][r],sac[3][r]));
            #pragma unroll
            for(int msk=1;msk<16;msk<<=1) mx = fmaxf(mx, __shfl_xor(mx, msk));
            pm[r]=mx;
        }
        float sf_[4];
        #pragma unroll
        for(int r=0;r<4;r++){
            float mn = fmaxf(m_r[r], pm[r]);
            float s  = exp2f(m_r[r]-mn);
            m_r[r]=mn; l_r[r]*=s; sf_[r]=s;
        }
        #pragma unroll
        for(int dt=0;dt<8;dt++){
            #pragma unroll
            for(int r=0;r<4;r++) ot[dt][r]*=sf_[r];
        }
        // ---- P = exp2(S-m), row sums, write P to per-wave LDS ----
        float psum[4]={0.f,0.f,0.f,0.f};
        #pragma unroll
        for(int t=0;t<4;t++){
            #pragma unroll
            for(int r=0;r<4;r++){
                float p = exp2f(sac[t][r]-m_r[r]);
                psum[r]+=p;
                int ql = lg*4+r;
                int addr = wave*2048 + ((ql*128 + (t*16+lr)*2) ^ ((ql&7)<<4));
                *(short*)(pls + addr) = f2bf(p);
            }
        }
        #pragma unroll
        for(int r=0;r<4;r++){
            float s2=psum[r];
            #pragma unroll
            for(int msk=1;msk<16;msk<<=1) s2 += __shfl_xor(s2, msk);
            l_r[r]+=s2;
        }
        // ---- O += P V ----
        #pragma unroll
        for(int kc=0;kc<2;kc++){
            int paddr = wave*2048 + ((lr*128 + kc*64 + lg*16) ^ ((lr&7)<<4));
            short8 pf = *(const short8*)(pls + paddr);
            #pragma unroll
            for(int dt=0;dt<8;dt++){
                int dd = dt*16 + lr;
                int vaddr = (dd*128 + kc*64 + lg*16) ^ ((dd&7)<<4);
                short8 vf = *(const short8*)(vls + vaddr);
                ot[dt] = MFMA16(pf, vf, ot[dt]);
            }
        }
    }

    // ---- epilogue: O / l, write fp32 ----
    float rinv[4];
    #pragma unroll
    for(int r=0;r<4;r++) rinv[r] = 1.0f / l_r[r];
    #pragma unroll
    for(int r=0;r<4;r++){
        int gq = q0 + wave*16 + lg*4 + r;
        float* op = out + ((size_t)(b*S_+gq)*H_ + h)*D_;
        #pragma unroll
        for(int dt=0;dt<8;dt++){
            op[dt*16+lr] = ot[dt][r]*rinv[r];
        }
    }
}

extern "C" void kernel_launch(void* const* d_in, const int* in_sizes, int n_in,
                              void* d_out, int out_size, void* d_ws, size_t ws_size,
                              hipStream_t stream) {
    const float* q = (const float*)d_in[0];
    const float* k = (const float*)d_in[1];
    const float* v = (const float*)d_in[2];
    float* out = (float*)d_out;
    dim3 grid(2*H_*(S_/QBLK));   // 2048
    dim3 block(256);
    attn_fwd<<<grid, block, 0, stream>>>(q, k, v, out);
}

// Round 2
// 353.374 us; speedup vs baseline: 2.5172x; 2.5172x over previous
//
#include <hip/hip_runtime.h>
#include <hip/hip_bf16.h>

typedef __attribute__((ext_vector_type(8))) short short8;
typedef __attribute__((ext_vector_type(4))) short short4v;
typedef __attribute__((ext_vector_type(4))) float f32x4;

#define MFMA16(a,b,c) __builtin_amdgcn_mfma_f32_16x16x32_bf16(a,b,c,0,0,0)

static __device__ __forceinline__ short f2bf(float f){
    union{float f;unsigned u;}x; x.f=f;
    unsigned r=(x.u+0x7FFFu+((x.u>>16)&1u))>>16;
    return (short)r;
}

static __device__ __forceinline__ void gl_lds16(const void* g, void* l){
    __builtin_amdgcn_global_load_lds(
        (const __attribute__((address_space(1))) unsigned int*)g,
        (__attribute__((address_space(3))) unsigned int*)l, 16, 0, 0);
}

// B=2, S=2048, H=32, HK=8, D=128, G=4
constexpr int S_=2048, H_=32, HK_=8, D_=128;
constexpr int QBLK=64, KVBLK=64;

// ---- prepass 1: K [B,S,HK,D] f32 -> kb [B,HK,S,D] bf16 ----
__global__ __launch_bounds__(256) void prep_k(const float* __restrict__ k, short* __restrict__ kb){
    int t = blockIdx.x*256 + threadIdx.x;     // 1,048,576 threads, 4 elems each
    int e = t*4;
    int d  = e & 127;
    int hk = (e>>7) & 7;
    int s  = (e>>10) & 2047;
    int b  = e>>21;
    f32x4 x = *(const f32x4*)(k + ((size_t)((b*S_+s)*HK_+hk))*D_ + d);
    short4v o;
    o[0]=f2bf(x[0]); o[1]=f2bf(x[1]); o[2]=f2bf(x[2]); o[3]=f2bf(x[3]);
    *(short4v*)(kb + ((size_t)((b*HK_+hk)*S_+s))*D_ + d) = o;
}

// ---- prepass 2: V [B,S,HK,D] f32 -> vt [B,HK,D,S] bf16 (transpose) ----
__global__ __launch_bounds__(256) void prep_vt(const float* __restrict__ v, short* __restrict__ vt){
    __shared__ short tile[64*65];
    int bid = blockIdx.x;                    // 2*8*32*2 = 1024 blocks
    int d0 = (bid & 1)*64;
    int s0 = ((bid>>1) & 31)*64;
    int hk = (bid>>6) & 7;
    int b  = bid>>9;
    int tid = threadIdx.x;
    #pragma unroll
    for(int i=0;i<4;i++){
        int idx = i*1024 + tid*4;
        int r = idx>>6, c = idx&63;          // r = s-local, c = d-local (mult of 4)
        f32x4 x = *(const f32x4*)(v + ((size_t)((b*S_+s0+r)*HK_+hk))*D_ + d0 + c);
        tile[(c+0)*65 + r] = f2bf(x[0]);
        tile[(c+1)*65 + r] = f2bf(x[1]);
        tile[(c+2)*65 + r] = f2bf(x[2]);
        tile[(c+3)*65 + r] = f2bf(x[3]);
    }
    __syncthreads();
    #pragma unroll
    for(int i=0;i<4;i++){
        int idx = i*1024 + tid*4;
        int dr = idx>>6, c = idx&63;         // dr = d-local, c = s-local (mult of 4)
        short4v o;
        o[0]=tile[dr*65+c]; o[1]=tile[dr*65+c+1]; o[2]=tile[dr*65+c+2]; o[3]=tile[dr*65+c+3];
        *(short4v*)(vt + ((size_t)((b*HK_+hk)*D_ + d0+dr))*S_ + s0 + c) = o;
    }
}

// ---- main attention kernel ----
__global__ __launch_bounds__(256) void attn_fwd(
    const float* __restrict__ q, const short* __restrict__ kb,
    const short* __restrict__ vtb, float* __restrict__ out)
{
    // double-buffered K [64][128]bf16 and V^T [128][64]bf16, XOR-swizzled
    __shared__ __align__(16) unsigned char kls[2][KVBLK*D_*2];   // 2x16KB
    __shared__ __align__(16) unsigned char vls[2][D_*KVBLK*2];   // 2x16KB
    __shared__ __align__(16) unsigned char pls[4][16*KVBLK*2];   // 4x2KB

    const int bid  = blockIdx.x;
    const int tile = 31 - (bid & 31);        // heavy blocks first
    const int h    = (bid >> 5) & 31;
    const int b    = bid >> 10;
    const int hk   = h >> 2;                 // G = 4

    const int tid  = threadIdx.x;
    const int wave = tid >> 6;
    const int lr   = tid & 15;
    const int lg   = (tid >> 4) & 3;

    const float qscale = 0.08838834764831845f * 1.4426950408889634f;
    const int q0 = tile * QBLK;

    const short* kt_base = kb  + (size_t)(b*HK_+hk)*S_*D_;
    const short* vt_base = vtb + (size_t)(b*HK_+hk)*D_*S_;

    // ---- Q fragments: 16 rows/wave, fp32->bf16, scale folded ----
    short8 qf[4];
    {
        const int qrow = q0 + wave*16 + lr;
        const float* qp = q + ((size_t)(b*S_ + qrow)*H_ + h)*D_;
        #pragma unroll
        for(int kk=0;kk<4;kk++){
            int d0 = kk*32 + lg*8;
            f32x4 a = *(const f32x4*)(qp + d0);
            f32x4 c = *(const f32x4*)(qp + d0 + 4);
            short8 f;
            f[0]=f2bf(a[0]*qscale); f[1]=f2bf(a[1]*qscale);
            f[2]=f2bf(a[2]*qscale); f[3]=f2bf(a[3]*qscale);
            f[4]=f2bf(c[0]*qscale); f[5]=f2bf(c[1]*qscale);
            f[6]=f2bf(c[2]*qscale); f[7]=f2bf(c[3]*qscale);
            qf[kk]=f;
        }
    }

    f32x4 ot[8];
    #pragma unroll
    for(int i=0;i<8;i++) ot[i]=(f32x4)0.f;
    float m_r[4], l_r[4];
    #pragma unroll
    for(int r=0;r<4;r++){ m_r[r]=-1e30f; l_r[r]=0.f; }

    // stage: global bf16 -> LDS via global_load_lds, inverse-swizzled source
    auto STAGE=[&](int bufi, int kvt){
        const int kv0 = kvt*KVBLK;
        const char* kg = (const char*)(kt_base + (size_t)kv0*D_);
        #pragma unroll
        for(int i=0;i<4;i++){
            int p = (i*256+tid)*16;
            int src = p ^ (((p>>8)&7)<<4);
            gl_lds16(kg + src, &kls[bufi][p]);
        }
        const char* vg = (const char*)vt_base + kv0*2;
        #pragma unroll
        for(int i=0;i<4;i++){
            int p = (i*256+tid)*16;
            int d = p>>7;
            int src = (p&127) ^ ((d&7)<<4);
            gl_lds16(vg + (size_t)d*(S_*2) + src, &vls[bufi][p]);
        }
    };

    const int nkv = tile + 1;
    STAGE(0, 0);
    __syncthreads();      // drains vmcnt(0): tile 0 staged
    int cur = 0;

    for(int kvt=0; kvt<nkv; ++kvt){
        const int kv0 = kvt*KVBLK;
        if (kvt+1 < nkv) STAGE(cur^1, kvt+1);

        // ---- S = Q K^T ----
        f32x4 sac[4];
        #pragma unroll
        for(int t=0;t<4;t++) sac[t]=(f32x4)0.f;
        #pragma unroll
        for(int t=0;t<4;t++){
            int kvr = t*16 + lr;
            #pragma unroll
            for(int kk=0;kk<4;kk++){
                int addr = (kvr*256 + kk*64 + lg*16) ^ ((kvr&7)<<4);
                short8 kf = *(const short8*)(&kls[cur][addr]);
                sac[t] = MFMA16(qf[kk], kf, sac[t]);
            }
        }
        // ---- causal mask (diagonal tile only) ----
        if (kvt == tile){
            #pragma unroll
            for(int t=0;t<4;t++){
                #pragma unroll
                for(int r=0;r<4;r++){
                    int gq  = q0 + wave*16 + lg*4 + r;
                    int gkv = kv0 + t*16 + lr;
                    if (gkv > gq) sac[t][r] = -1e30f;
                }
            }
        }
        // ---- online softmax (base-2) ----
        float pm[4];
        #pragma unroll
        for(int r=0;r<4;r++){
            float mx = fmaxf(fmaxf(sac[0][r],sac[1][r]),fmaxf(sac[2][r],sac[3][r]));
            #pragma unroll
            for(int msk=1;msk<16;msk<<=1) mx = fmaxf(mx, __shfl_xor(mx, msk));
            pm[r]=mx;
        }
        float sf_[4];
        #pragma unroll
        for(int r=0;r<4;r++){
            float mn = fmaxf(m_r[r], pm[r]);
            float s  = exp2f(m_r[r]-mn);
            m_r[r]=mn; l_r[r]*=s; sf_[r]=s;
        }
        #pragma unroll
        for(int dt=0;dt<8;dt++){
            #pragma unroll
            for(int r=0;r<4;r++) ot[dt][r]*=sf_[r];
        }
        // ---- P = exp2(S-m), row sums, P -> per-wave LDS ----
        float psum[4]={0.f,0.f,0.f,0.f};
        #pragma unroll
        for(int t=0;t<4;t++){
            #pragma unroll
            for(int r=0;r<4;r++){
                float p = exp2f(sac[t][r]-m_r[r]);
                psum[r]+=p;
                int ql = lg*4+r;
                int addr = (ql*128 + (t*16+lr)*2) ^ ((ql&7)<<4);
                *(short*)(&pls[wave][addr]) = f2bf(p);
            }
        }
        #pragma unroll
        for(int r=0;r<4;r++){
            float s2=psum[r];
            #pragma unroll
            for(int msk=1;msk<16;msk<<=1) s2 += __shfl_xor(s2, msk);
            l_r[r]+=s2;
        }
        // ---- O += P V ----
        #pragma unroll
        for(int kc=0;kc<2;kc++){
            int paddr = (lr*128 + kc*64 + lg*16) ^ ((lr&7)<<4);
            short8 pf = *(const short8*)(&pls[wave][paddr]);
            #pragma unroll
            for(int dt=0;dt<8;dt++){
                int dd = dt*16 + lr;
                int vaddr = (dd*128 + kc*64 + lg*16) ^ ((dd&7)<<4);
                short8 vf = *(const short8*)(&vls[cur][vaddr]);
                ot[dt] = MFMA16(pf, vf, ot[dt]);
            }
        }
        __syncthreads();   // stage of kvt+1 done; all waves done reading buf cur
        cur ^= 1;
    }

    // ---- epilogue ----
    float rinv[4];
    #pragma unroll
    for(int r=0;r<4;r++) rinv[r] = 1.0f / l_r[r];
    #pragma unroll
    for(int r=0;r<4;r++){
        int gq = q0 + wave*16 + lg*4 + r;
        float* op = out + ((size_t)(b*S_+gq)*H_ + h)*D_;
        #pragma unroll
        for(int dt=0;dt<8;dt++){
            op[dt*16+lr] = ot[dt][r]*rinv[r];
        }
    }
}

extern "C" void kernel_launch(void* const* d_in, const int* in_sizes, int n_in,
                              void* d_out, int out_size, void* d_ws, size_t ws_size,
                              hipStream_t stream) {
    const float* q = (const float*)d_in[0];
    const float* k = (const float*)d_in[1];
    const float* v = (const float*)d_in[2];
    float* out = (float*)d_out;

    short* kb = (short*)d_ws;                                  // 8,388,608 B
    short* vt = (short*)((char*)d_ws + (size_t)2*HK_*S_*D_*2); // next 8,388,608 B

    prep_k <<<dim3(4096), dim3(256), 0, stream>>>(k, kb);
    prep_vt<<<dim3(1024), dim3(256), 0, stream>>>(v, vt);

    dim3 grid(2*H_*(S_/QBLK));   // 2048
    dim3 block(256);
    attn_fwd<<<grid, block, 0, stream>>>(q, kb, vt, out);
}

// Round 4
// 120.623 us; speedup vs baseline: 7.3742x; 2.9296x over previous
//
#include <hip/hip_runtime.h>
#include <hip/hip_bf16.h>

typedef __attribute__((ext_vector_type(8))) short short8;
typedef __attribute__((ext_vector_type(4))) short short4v;
typedef __attribute__((ext_vector_type(4))) float f32x4;
typedef __attribute__((ext_vector_type(16))) float f32x16;

#define MFMA32(a,b,c) __builtin_amdgcn_mfma_f32_32x32x16_bf16(a,b,c,0,0,0)

static __device__ __forceinline__ short f2bf(float f){
    union{float f;unsigned u;}x; x.f=f;
    unsigned r=(x.u+0x7FFFu+((x.u>>16)&1u))>>16;
    return (short)r;
}

static __device__ __forceinline__ unsigned pkbf(float lo, float hi){
    unsigned r;
    asm("v_cvt_pk_bf16_f32 %0, %1, %2" : "=v"(r) : "v"(lo), "v"(hi));
    return r;
}

static __device__ __forceinline__ void gl_lds16(const void* g, void* l){
    __builtin_amdgcn_global_load_lds(
        (const __attribute__((address_space(1))) unsigned int*)g,
        (__attribute__((address_space(3))) unsigned int*)l, 16, 0, 0);
}

// build PV B-fragment: lane (ln,hi) needs P[q=ln][kv = chunk + hi*8 + e], e=0..7.
// own regs hold kv (r&3)+8*(r>>2)+4*hi; partner (lane^32) holds the other half.
// Cross-half exchange via __shfl_xor(...,32) — certain semantics.
static __device__ __forceinline__ short8 pfrag(int hi,
        float e0,float e1,float e2,float e3,
        float e4,float e5,float e6,float e7){
    unsigned a01 = pkbf(e0,e1), a23 = pkbf(e2,e3);
    unsigned a45 = pkbf(e4,e5), a67 = pkbf(e6,e7);
    unsigned b01 = __shfl_xor(a01, 32);
    unsigned b23 = __shfl_xor(a23, 32);
    unsigned b45 = __shfl_xor(a45, 32);
    unsigned b67 = __shfl_xor(a67, 32);
    union{ unsigned u[4]; short8 s; } w;
    w.u[0] = hi ? b45 : a01;   // hi=0: kv c+0,1   | hi=1: kv c+8,9
    w.u[1] = hi ? b67 : a23;   // hi=0: kv c+2,3   | hi=1: kv c+10,11
    w.u[2] = hi ? a45 : b01;   // hi=0: kv c+4,5   | hi=1: kv c+12,13
    w.u[3] = hi ? a67 : b23;   // hi=0: kv c+6,7   | hi=1: kv c+14,15
    return w.s;
}

// B=2, S=2048, H=32, HK=8, D=128, G=4
constexpr int S_=2048, H_=32, HK_=8, D_=128;
constexpr int KVBLK=64;

// ---- prepass 1: K [B,S,HK,D] f32 -> kb [B,HK,S,D] bf16 ----
__global__ __launch_bounds__(256) void prep_k(const float* __restrict__ k, short* __restrict__ kb){
    int t = blockIdx.x*256 + threadIdx.x;
    int e = t*4;
    int d  = e & 127;
    int hk = (e>>7) & 7;
    int s  = (e>>10) & 2047;
    int b  = e>>21;
    f32x4 x = *(const f32x4*)(k + ((size_t)((b*S_+s)*HK_+hk))*D_ + d);
    short4v o;
    o[0]=f2bf(x[0]); o[1]=f2bf(x[1]); o[2]=f2bf(x[2]); o[3]=f2bf(x[3]);
    *(short4v*)(kb + ((size_t)((b*HK_+hk)*S_+s))*D_ + d) = o;
}

// ---- prepass 2: V [B,S,HK,D] f32 -> vt [B,HK,D,S] bf16 (transpose) ----
__global__ __launch_bounds__(256) void prep_vt(const float* __restrict__ v, short* __restrict__ vt){
    __shared__ short tile[64*65];
    int bid = blockIdx.x;
    int d0 = (bid & 1)*64;
    int s0 = ((bid>>1) & 31)*64;
    int hk = (bid>>6) & 7;
    int b  = bid>>9;
    int tid = threadIdx.x;
    #pragma unroll
    for(int i=0;i<4;i++){
        int idx = i*1024 + tid*4;
        int r = idx>>6, c = idx&63;
        f32x4 x = *(const f32x4*)(v + ((size_t)((b*S_+s0+r)*HK_+hk))*D_ + d0 + c);
        tile[(c+0)*65 + r] = f2bf(x[0]);
        tile[(c+1)*65 + r] = f2bf(x[1]);
        tile[(c+2)*65 + r] = f2bf(x[2]);
        tile[(c+3)*65 + r] = f2bf(x[3]);
    }
    __syncthreads();
    #pragma unroll
    for(int i=0;i<4;i++){
        int idx = i*1024 + tid*4;
        int dr = idx>>6, c = idx&63;
        short4v o;
        o[0]=tile[dr*65+c]; o[1]=tile[dr*65+c+1]; o[2]=tile[dr*65+c+2]; o[3]=tile[dr*65+c+3];
        *(short4v*)(vt + ((size_t)((b*HK_+hk)*D_ + d0+dr))*S_ + s0 + c) = o;
    }
}

// ---- main attention: 8 waves x 32 q-rows, swapped QK^T, 32x32 MFMA ----
__global__ __launch_bounds__(512,2) void attn_fwd(
    const float* __restrict__ q, const short* __restrict__ kb,
    const short* __restrict__ vtb, float* __restrict__ out)
{
    // K tile [64][128]bf16 (rows 256B) and V^T tile [128][64]bf16 (rows 128B),
    // double-buffered, XOR-swizzled (^((row&7)<<4))
    __shared__ __align__(16) unsigned char kls[2][KVBLK*D_*2];   // 2x16KB
    __shared__ __align__(16) unsigned char vls[2][D_*KVBLK*2];   // 2x16KB

    const int bid  = blockIdx.x;                 // 512 blocks
    const int qt   = 7 - (bid >> 6);             // heavy q-tiles first
    const int head = bid & 63;
    const int b    = head >> 5;
    const int h    = head & 31;
    const int hk   = h >> 2;
    const int q0   = qt * 256;

    const int tid  = threadIdx.x;
    const int wave = tid >> 6;
    const int ln   = tid & 31;
    const int hi   = (tid >> 5) & 1;
    const int qg   = q0 + wave*32 + ln;          // this lane's q row/column

    const float qscale = 0.08838834764831845f * 1.4426950408889634f; // /sqrt(D)*log2e

    const short* kt_base = kb  + (size_t)(b*HK_+hk)*S_*D_;
    const short* vt_base = vtb + (size_t)(b*HK_+hk)*D_*S_;

    // ---- Q fragments: lane holds Q[qg][16kk+8hi .. +7], scaled ----
    short8 qf[8];
    {
        const float* qp = q + ((size_t)(b*S_ + qg)*H_ + h)*D_;
        #pragma unroll
        for(int kk=0;kk<8;kk++){
            int d0 = kk*16 + hi*8;
            f32x4 a = *(const f32x4*)(qp + d0);
            f32x4 c = *(const f32x4*)(qp + d0 + 4);
            union{ unsigned u[4]; short8 s; } w;
            w.u[0]=pkbf(a[0]*qscale, a[1]*qscale);
            w.u[1]=pkbf(a[2]*qscale, a[3]*qscale);
            w.u[2]=pkbf(c[0]*qscale, c[1]*qscale);
            w.u[3]=pkbf(c[2]*qscale, c[3]*qscale);
            qf[kk]=w.s;
        }
    }

    f32x16 oac[4];
    #pragma unroll
    for(int dt=0;dt<4;dt++) oac[dt] = (f32x16)0.f;
    float m = -1e30f, l = 0.f;

    auto STAGE = [&](int bufi, int kvt){
        const char* kg = (const char*)(kt_base + (size_t)kvt*KVBLK*D_);
        #pragma unroll
        for(int i=0;i<2;i++){
            int p = (i*512 + tid)*16;
            int src = p ^ (((p>>8)&7)<<4);
            gl_lds16(kg + src, &kls[bufi][p]);
        }
        const char* vg = (const char*)vt_base + (size_t)kvt*KVBLK*2;
        #pragma unroll
        for(int i=0;i<2;i++){
            int p = (i*512 + tid)*16;
            int d = p>>7;
            int src = (p&127) ^ ((d&7)<<4);
            gl_lds16(vg + (size_t)d*(S_*2) + src, &vls[bufi][p]);
        }
    };

    const int nkv     = q0/64 + 4;
    const int kvmax_w = (q0 + wave*32 + 31) >> 6;   // last tile this wave needs

    STAGE(0, 0);
    __syncthreads();
    int cur = 0;

    for(int kvt=0; kvt<nkv; ++kvt){
        if (kvt+1 < nkv) STAGE(cur^1, kvt+1);

        if (kvt <= kvmax_w){
            const int kv0 = kvt*64;
            // ---- S^T = K . Q^T : lane col q=qg, 32 kv rows across regs+hi ----
            f32x16 sa0=(f32x16)0.f, sa1=(f32x16)0.f;
            const int sz = (ln&7)<<4;
            #pragma unroll
            for(int kk=0;kk<8;kk++){
                int c = kk*32 + hi*16;
                short8 k0 = *(const short8*)&kls[cur][(ln*256 + c) ^ sz];
                short8 k1 = *(const short8*)&kls[cur][((ln+32)*256 + c) ^ sz];
                sa0 = MFMA32(k0, qf[kk], sa0);
                sa1 = MFMA32(k1, qf[kk], sa1);
            }
            // ---- causal mask (diagonal band only) ----
            if (kv0 + 63 > q0 + wave*32){
                #pragma unroll
                for(int r=0;r<16;r++){
                    int kvl = (r&3) + 8*(r>>2) + 4*hi;
                    if (kv0 + kvl      > qg) sa0[r] = -1e30f;
                    if (kv0 + 32 + kvl > qg) sa1[r] = -1e30f;
                }
            }
            // ---- online softmax, fully in-register (shfl across hi-halves) ----
            float pm = sa0[0];
            #pragma unroll
            for(int r=1;r<16;r++) pm = fmaxf(pm, sa0[r]);
            #pragma unroll
            for(int r=0;r<16;r++) pm = fmaxf(pm, sa1[r]);
            pm = fmaxf(pm, __shfl_xor(pm, 32));
            float mn = fmaxf(m, pm);
            float sf = __builtin_amdgcn_exp2f(m - mn);
            m = mn;
            float ps = 0.f;
            #pragma unroll
            for(int r=0;r<16;r++){ sa0[r] = __builtin_amdgcn_exp2f(sa0[r]-mn); ps += sa0[r]; }
            #pragma unroll
            for(int r=0;r<16;r++){ sa1[r] = __builtin_amdgcn_exp2f(sa1[r]-mn); ps += sa1[r]; }
            l = l*sf + (ps + __shfl_xor(ps, 32));
            #pragma unroll
            for(int dt=0;dt<4;dt++){
                #pragma unroll
                for(int r=0;r<16;r++) oac[dt][r] *= sf;
            }
            // ---- P -> bf16 PV fragments (cvt_pk + shfl_xor 32) ----
            short8 pa0 = pfrag(hi, sa0[0],sa0[1],sa0[2], sa0[3], sa0[4], sa0[5], sa0[6], sa0[7]);
            short8 pa1 = pfrag(hi, sa0[8],sa0[9],sa0[10],sa0[11],sa0[12],sa0[13],sa0[14],sa0[15]);
            short8 pa2 = pfrag(hi, sa1[0],sa1[1],sa1[2], sa1[3], sa1[4], sa1[5], sa1[6], sa1[7]);
            short8 pa3 = pfrag(hi, sa1[8],sa1[9],sa1[10],sa1[11],sa1[12],sa1[13],sa1[14],sa1[15]);
            // ---- O^T += V^T . P^T : lane col q=qg, d rows across regs+hi ----
            #pragma unroll
            for(int dt=0;dt<4;dt++){
                int rb = (dt*32 + ln)*128;
                short8 v0 = *(const short8*)&vls[cur][(rb +   0 + hi*16) ^ sz];
                oac[dt] = MFMA32(v0, pa0, oac[dt]);
                short8 v1 = *(const short8*)&vls[cur][(rb +  32 + hi*16) ^ sz];
                oac[dt] = MFMA32(v1, pa1, oac[dt]);
                short8 v2 = *(const short8*)&vls[cur][(rb +  64 + hi*16) ^ sz];
                oac[dt] = MFMA32(v2, pa2, oac[dt]);
                short8 v3 = *(const short8*)&vls[cur][(rb +  96 + hi*16) ^ sz];
                oac[dt] = MFMA32(v3, pa3, oac[dt]);
            }
        }
        __syncthreads();
        cur ^= 1;
    }

    // ---- epilogue: O[qg][d] = O^T regs / l ; d = 32dt + 8rr + 4hi + j ----
    float rinv = 1.0f / l;
    float* op = out + ((size_t)(b*S_ + qg)*H_ + h)*D_;
    #pragma unroll
    for(int dt=0;dt<4;dt++){
        #pragma unroll
        for(int rr=0;rr<4;rr++){
            f32x4 o4;
            o4[0]=oac[dt][rr*4+0]*rinv;
            o4[1]=oac[dt][rr*4+1]*rinv;
            o4[2]=oac[dt][rr*4+2]*rinv;
            o4[3]=oac[dt][rr*4+3]*rinv;
            *(f32x4*)(op + dt*32 + rr*8 + hi*4) = o4;
        }
    }
}

extern "C" void kernel_launch(void* const* d_in, const int* in_sizes, int n_in,
                              void* d_out, int out_size, void* d_ws, size_t ws_size,
                              hipStream_t stream) {
    const float* q = (const float*)d_in[0];
    const float* k = (const float*)d_in[1];
    const float* v = (const float*)d_in[2];
    float* out = (float*)d_out;

    short* kb = (short*)d_ws;                                  // 8 MB
    short* vt = (short*)((char*)d_ws + (size_t)2*HK_*S_*D_*2); // next 8 MB

    prep_k <<<dim3(4096), dim3(256), 0, stream>>>(k, kb);
    prep_vt<<<dim3(1024), dim3(256), 0, stream>>>(v, vt);

    attn_fwd<<<dim3(512), dim3(512), 0, stream>>>(q, kb, vt, out);
}

// Round 5
// 116.480 us; speedup vs baseline: 7.6365x; 1.0356x over previous
//
#include <hip/hip_runtime.h>
#include <hip/hip_bf16.h>

typedef __attribute__((ext_vector_type(8))) short short8;
typedef __attribute__((ext_vector_type(4))) short short4v;
typedef __attribute__((ext_vector_type(4))) float f32x4;
typedef __attribute__((ext_vector_type(16))) float f32x16;

#define MFMA32(a,b,c) __builtin_amdgcn_mfma_f32_32x32x16_bf16(a,b,c,0,0,0)

static __device__ __forceinline__ short f2bf(float f){
    union{float f;unsigned u;}x; x.f=f;
    unsigned r=(x.u+0x7FFFu+((x.u>>16)&1u))>>16;
    return (short)r;
}

static __device__ __forceinline__ unsigned pkbf(float lo, float hi){
    unsigned r;
    asm("v_cvt_pk_bf16_f32 %0, %1, %2" : "=v"(r) : "v"(lo), "v"(hi));
    return r;
}

static __device__ __forceinline__ void gl_lds16(const void* g, void* l){
    __builtin_amdgcn_global_load_lds(
        (const __attribute__((address_space(1))) unsigned int*)g,
        (__attribute__((address_space(3))) unsigned int*)l, 16, 0, 0);
}

// build PV B-fragment: lane (ln,hi) needs P[q=ln][kv = chunk + hi*8 + e], e=0..7.
// own regs hold kv (r&3)+8*(r>>2)+4*hi; partner (lane^32) holds the other half.
static __device__ __forceinline__ short8 pfrag(int hi,
        float e0,float e1,float e2,float e3,
        float e4,float e5,float e6,float e7){
    unsigned a01 = pkbf(e0,e1), a23 = pkbf(e2,e3);
    unsigned a45 = pkbf(e4,e5), a67 = pkbf(e6,e7);
    unsigned b01 = __shfl_xor(a01, 32);
    unsigned b23 = __shfl_xor(a23, 32);
    unsigned b45 = __shfl_xor(a45, 32);
    unsigned b67 = __shfl_xor(a67, 32);
    union{ unsigned u[4]; short8 s; } w;
    w.u[0] = hi ? b45 : a01;
    w.u[1] = hi ? b67 : a23;
    w.u[2] = hi ? a45 : b01;
    w.u[3] = hi ? a67 : b23;
    return w.s;
}

// B=2, S=2048, H=32, HK=8, D=128, G=4
constexpr int S_=2048, H_=32, HK_=8, D_=128;
constexpr int KVBLK=64;

// ---- fused prepass: K repack -> bf16 [B,HK,S,D]; V transpose -> bf16 [B,HK,D,S] ----
__global__ __launch_bounds__(256) void prep(const float* __restrict__ k, const float* __restrict__ v,
                                            short* __restrict__ kb, short* __restrict__ vt){
    __shared__ short tile[64*65];
    int bid = blockIdx.x;
    if (bid < 4096){
        int t = bid*256 + threadIdx.x;
        int e = t*4;
        int d  = e & 127;
        int hk = (e>>7) & 7;
        int s  = (e>>10) & 2047;
        int b  = e>>21;
        f32x4 x = *(const f32x4*)(k + ((size_t)((b*S_+s)*HK_+hk))*D_ + d);
        short4v o;
        o[0]=f2bf(x[0]); o[1]=f2bf(x[1]); o[2]=f2bf(x[2]); o[3]=f2bf(x[3]);
        *(short4v*)(kb + ((size_t)((b*HK_+hk)*S_+s))*D_ + d) = o;
    } else {
        bid -= 4096;
        int d0 = (bid & 1)*64;
        int s0 = ((bid>>1) & 31)*64;
        int hk = (bid>>6) & 7;
        int b  = bid>>9;
        int tid = threadIdx.x;
        #pragma unroll
        for(int i=0;i<4;i++){
            int idx = i*1024 + tid*4;
            int r = idx>>6, c = idx&63;
            f32x4 x = *(const f32x4*)(v + ((size_t)((b*S_+s0+r)*HK_+hk))*D_ + d0 + c);
            tile[(c+0)*65 + r] = f2bf(x[0]);
            tile[(c+1)*65 + r] = f2bf(x[1]);
            tile[(c+2)*65 + r] = f2bf(x[2]);
            tile[(c+3)*65 + r] = f2bf(x[3]);
        }
        __syncthreads();
        #pragma unroll
        for(int i=0;i<4;i++){
            int idx = i*1024 + tid*4;
            int dr = idx>>6, c = idx&63;
            short4v o;
            o[0]=tile[dr*65+c]; o[1]=tile[dr*65+c+1]; o[2]=tile[dr*65+c+2]; o[3]=tile[dr*65+c+3];
            *(short4v*)(vt + ((size_t)((b*HK_+hk)*D_ + d0+dr))*S_ + s0 + c) = o;
        }
    }
}

// ---- main attention: 4 waves x 32 q-rows, two paired q-chunks (c, 15-c) ----
__global__ __launch_bounds__(256,2) void attn_fwd(
    const float* __restrict__ q, const short* __restrict__ kb,
    const short* __restrict__ vtb, float* __restrict__ out)
{
    // K tile [64][128]bf16 (rows 256B), V^T tile [128][64]bf16 (rows 128B),
    // double-buffered, XOR-swizzled (^((row&7)<<4))
    __shared__ __align__(16) unsigned char kls[2][KVBLK*D_*2];   // 2x16KB
    __shared__ __align__(16) unsigned char vls[2][D_*KVBLK*2];   // 2x16KB

    const int bid  = blockIdx.x;                 // 512 blocks
    // XCD-aware: consecutive work per XCD shares (b,hk) KV in its L2
    const int wg   = (bid & 7)*64 + (bid >> 3);  // bijective, 512 % 8 == 0
    const int kvg  = wg >> 5;                    // 0..15 = b*8+hk
    const int b    = kvg >> 3;
    const int hk   = kvg & 7;
    const int rr_  = wg & 31;
    const int h    = hk*4 + (rr_ >> 3);
    const int pair = rr_ & 7;                    // q-chunk pair (pair, 15-pair)

    const int tid  = threadIdx.x;
    const int wave = tid >> 6;                   // 0..3
    const int ln   = tid & 31;
    const int hi   = (tid >> 5) & 1;

    const float qscale = 0.08838834764831845f * 1.4426950408889634f; // /sqrt(D)*log2e

    const short* kt_base = kb  + (size_t)(b*HK_+hk)*S_*D_;
    const short* vt_base = vtb + (size_t)(b*HK_+hk)*D_*S_;

    auto STAGE = [&](int bufi, int kvt){
        const char* kg = (const char*)(kt_base + (size_t)kvt*KVBLK*D_);
        #pragma unroll
        for(int i=0;i<4;i++){
            int p = (i*256 + tid)*16;
            int src = p ^ (((p>>8)&7)<<4);
            gl_lds16(kg + src, &kls[bufi][p]);
        }
        const char* vg = (const char*)vt_base + (size_t)kvt*KVBLK*2;
        #pragma unroll
        for(int i=0;i<4;i++){
            int p = (i*256 + tid)*16;
            int d = p>>7;
            int src = (p&127) ^ ((d&7)<<4);
            gl_lds16(vg + (size_t)d*(S_*2) + src, &vls[bufi][p]);
        }
    };

    int cur = 0;
    STAGE(0, 0);
    __syncthreads();

    for(int phase=0; phase<2; ++phase){
        const int c      = phase ? pair : 15-pair;   // heavy chunk first
        const int nkv    = 2*c + 2;
        const int kvmaxw = 2*c + (wave >> 1);        // waves 0,1 skip last tile
        const int qg     = c*128 + wave*32 + ln;

        // ---- Q fragments for this chunk ----
        short8 qf[8];
        {
            const float* qp = q + ((size_t)(b*S_ + qg)*H_ + h)*D_;
            #pragma unroll
            for(int kk=0;kk<8;kk++){
                int d0 = kk*16 + hi*8;
                f32x4 a = *(const f32x4*)(qp + d0);
                f32x4 cc= *(const f32x4*)(qp + d0 + 4);
                union{ unsigned u[4]; short8 s; } w;
                w.u[0]=pkbf(a[0]*qscale, a[1]*qscale);
                w.u[1]=pkbf(a[2]*qscale, a[3]*qscale);
                w.u[2]=pkbf(cc[0]*qscale, cc[1]*qscale);
                w.u[3]=pkbf(cc[2]*qscale, cc[3]*qscale);
                qf[kk]=w.s;
            }
        }

        f32x16 oac[4];
        #pragma unroll
        for(int dt=0;dt<4;dt++) oac[dt] = (f32x16)0.f;
        float m = -1e30f, l = 0.f;

        for(int kvt=0; kvt<nkv; ++kvt){
            int nxt = (kvt+1 < nkv) ? (kvt+1) : (phase==0 ? 0 : -1);
            if (nxt >= 0) STAGE(cur^1, nxt);

            if (kvt <= kvmaxw){
                const int kv0 = kvt*64;
                // ---- S^T = K . Q^T ----
                f32x16 sa0=(f32x16)0.f, sa1=(f32x16)0.f;
                const int sz = (ln&7)<<4;
                __builtin_amdgcn_s_setprio(1);
                #pragma unroll
                for(int kk=0;kk<8;kk++){
                    int cb = kk*32 + hi*16;
                    short8 k0 = *(const short8*)&kls[cur][(ln*256 + cb) ^ sz];
                    short8 k1 = *(const short8*)&kls[cur][((ln+32)*256 + cb) ^ sz];
                    sa0 = MFMA32(k0, qf[kk], sa0);
                    sa1 = MFMA32(k1, qf[kk], sa1);
                }
                __builtin_amdgcn_s_setprio(0);
                // ---- causal mask (diagonal band only) ----
                if (kv0 + 63 > c*128 + wave*32){
                    #pragma unroll
                    for(int r=0;r<16;r++){
                        int kvl = (r&3) + 8*(r>>2) + 4*hi;
                        if (kv0 + kvl      > qg) sa0[r] = -1e30f;
                        if (kv0 + 32 + kvl > qg) sa1[r] = -1e30f;
                    }
                }
                // ---- online softmax with defer-max (THR=8, log2 domain) ----
                float pm = sa0[0];
                #pragma unroll
                for(int r=1;r<16;r++) pm = fmaxf(pm, sa0[r]);
                #pragma unroll
                for(int r=0;r<16;r++) pm = fmaxf(pm, sa1[r]);
                pm = fmaxf(pm, __shfl_xor(pm, 32));
                if (!__all(pm <= m + 8.f)){
                    float mn = fmaxf(m, pm);
                    float sf = __builtin_amdgcn_exp2f(m - mn);
                    m = mn; l *= sf;
                    #pragma unroll
                    for(int dt=0;dt<4;dt++){
                        #pragma unroll
                        for(int r=0;r<16;r++) oac[dt][r] *= sf;
                    }
                }
                float ps = 0.f;
                #pragma unroll
                for(int r=0;r<16;r++){ sa0[r] = __builtin_amdgcn_exp2f(sa0[r]-m); ps += sa0[r]; }
                #pragma unroll
                for(int r=0;r<16;r++){ sa1[r] = __builtin_amdgcn_exp2f(sa1[r]-m); ps += sa1[r]; }
                l += ps + __shfl_xor(ps, 32);
                // ---- P -> bf16 PV fragments ----
                short8 pa0 = pfrag(hi, sa0[0],sa0[1],sa0[2], sa0[3], sa0[4], sa0[5], sa0[6], sa0[7]);
                short8 pa1 = pfrag(hi, sa0[8],sa0[9],sa0[10],sa0[11],sa0[12],sa0[13],sa0[14],sa0[15]);
                short8 pa2 = pfrag(hi, sa1[0],sa1[1],sa1[2], sa1[3], sa1[4], sa1[5], sa1[6], sa1[7]);
                short8 pa3 = pfrag(hi, sa1[8],sa1[9],sa1[10],sa1[11],sa1[12],sa1[13],sa1[14],sa1[15]);
                // ---- O^T += V^T . P^T ----
                __builtin_amdgcn_s_setprio(1);
                #pragma unroll
                for(int dt=0;dt<4;dt++){
                    int rb = (dt*32 + ln)*128;
                    short8 v0 = *(const short8*)&vls[cur][(rb +   0 + hi*16) ^ sz];
                    oac[dt] = MFMA32(v0, pa0, oac[dt]);
                    short8 v1 = *(const short8*)&vls[cur][(rb +  32 + hi*16) ^ sz];
                    oac[dt] = MFMA32(v1, pa1, oac[dt]);
                    short8 v2 = *(const short8*)&vls[cur][(rb +  64 + hi*16) ^ sz];
                    oac[dt] = MFMA32(v2, pa2, oac[dt]);
                    short8 v3 = *(const short8*)&vls[cur][(rb +  96 + hi*16) ^ sz];
                    oac[dt] = MFMA32(v3, pa3, oac[dt]);
                }
                __builtin_amdgcn_s_setprio(0);
            }
            __syncthreads();
            cur ^= 1;
        }

        // ---- epilogue for this chunk: O[qg][d] = O^T regs / l ----
        float rinv = 1.0f / l;
        float* op = out + ((size_t)(b*S_ + qg)*H_ + h)*D_;
        #pragma unroll
        for(int dt=0;dt<4;dt++){
            #pragma unroll
            for(int rr=0;rr<4;rr++){
                f32x4 o4;
                o4[0]=oac[dt][rr*4+0]*rinv;
                o4[1]=oac[dt][rr*4+1]*rinv;
                o4[2]=oac[dt][rr*4+2]*rinv;
                o4[3]=oac[dt][rr*4+3]*rinv;
                *(f32x4*)(op + dt*32 + rr*8 + hi*4) = o4;
            }
        }
    }
}

extern "C" void kernel_launch(void* const* d_in, const int* in_sizes, int n_in,
                              void* d_out, int out_size, void* d_ws, size_t ws_size,
                              hipStream_t stream) {
    const float* q = (const float*)d_in[0];
    const float* k = (const float*)d_in[1];
    const float* v = (const float*)d_in[2];
    float* out = (float*)d_out;

    short* kb = (short*)d_ws;                                  // 8 MB
    short* vt = (short*)((char*)d_ws + (size_t)2*HK_*S_*D_*2); // next 8 MB

    prep<<<dim3(4096+1024), dim3(256), 0, stream>>>(k, v, kb, vt);
    attn_fwd<<<dim3(512), dim3(256), 0, stream>>>(q, kb, vt, out);
}